// Round 8
// baseline (395.636 us; speedup 1.0000x reference)
//
#include <hip/hip_runtime.h>
#include <cstdint>
#include <cstddef>

typedef __bf16 bf16;
typedef __attribute__((ext_vector_type(4))) __bf16 bf16x4;
typedef __attribute__((ext_vector_type(8))) __bf16 bf16x8;
typedef __attribute__((ext_vector_type(4))) float floatx4;
typedef __attribute__((ext_vector_type(4))) short short4v;

#define MFMA16(a, b, c) __builtin_amdgcn_mfma_f32_16x16x32_bf16((a), (b), (c), 0, 0, 0)

// K=16 bf16 MFMA: A[m=l16][k=quad*4+j], B[n=l16][k=quad*4+j], C row=quad*4+r col=l16
__device__ __forceinline__ floatx4 MFMAK16(bf16x4 a, bf16x4 b, floatx4 c) {
#if __has_builtin(__builtin_amdgcn_mfma_f32_16x16x16bf16_1k)
  return __builtin_amdgcn_mfma_f32_16x16x16bf16_1k(
      __builtin_bit_cast(short4v, a), __builtin_bit_cast(short4v, b), c, 0, 0, 0);
#else
  floatx4 d;
  asm("v_mfma_f32_16x16x16_bf16 %0, %1, %2, %3"
      : "=v"(d)
      : "v"(a), "v"(b), "v"(c));
  return d;
#endif
}

constexpr int DMODEL = 1024;
constexpr int NH = 16;
constexpr int DKH = 64;
constexpr int B_ = 2;
constexpr int S_ = 2048;
constexpr int MTOT = B_ * S_;  // 4096
constexpr float CEXP = 0.125f * 1.44269504f;  // log2(e)/sqrt(64), folded into Q

// async global->LDS, 16B/lane; LDS dest = wave-uniform base + lane*16
__device__ __forceinline__ void load_lds16(const void* g, void* l) {
  __builtin_amdgcn_global_load_lds(
      (const __attribute__((address_space(1))) uint32_t*)g,
      (__attribute__((address_space(3))) uint32_t*)l, 16, 0, 0);
}

// ---------------------------------------------------------------------------
// bf16 LDS tiles: 64-col rows (8 x 16B chunks/row), chunk swizzle
// s = c ^ (row & 7); reads via frag64 (b128) / frag64h (b64) -> <=2-way banks.
// ---------------------------------------------------------------------------
__device__ __forceinline__ bf16x8 frag64(const bf16* lds, int row, int p) {
  int s = p ^ (row & 7);
  return *(const bf16x8*)&lds[row * 64 + s * 8];
}
// 8B read at global chunk p (16B units), sub-half h (0/1)
__device__ __forceinline__ bf16x4 frag64h(const bf16* lds, int row, int p, int h) {
  int s = p ^ (row & 7);
  return *(const bf16x4*)&lds[row * 64 + s * 8 + h * 4];
}

// ---------------------------------------------------------------------------
// fp32 LDS tiles: 64-col rows (16 x 16B chunks of 4 floats). Pair-preserving
// XOR swizzle: LDS slot sc holds global chunk sc ^ ((r&7)<<1) -- bit0 (chunk
// pair parity) preserved so an 8-float (2-chunk) group stays contiguous and
// one b128-pair read covers it. Read: pair t -> slot pair 2u,2u+1 with
// u = t ^ (r&7); 16 lanes spread over 8 distinct 32B columns -> <=2-way.
// Conversion fp32->bf16 happens on fragment read (free VALU slack).
// ---------------------------------------------------------------------------
// NCH = 16B-chunks per thread = R*16/256
template <int NCH>
__device__ __forceinline__ void stage_f32(const float* __restrict__ src,
                                          float* lds, int ldg, int wave,
                                          int lane) {
#pragma unroll
  for (int i = 0; i < NCH; ++i) {
    int cb = (wave * NCH + i) * 64;
    int c = cb + lane;
    int r = c >> 4;
    int sc = c & 15;
    int csrc = sc ^ ((r & 7) << 1);
    load_lds16(&src[(size_t)r * ldg + csrc * 4], &lds[cb * 4]);
  }
}
// read global k-pair t (k = t*8 .. t*8+7) of row, convert to bf16x8
__device__ __forceinline__ bf16x8 fragf(const float* lds, int row, int t) {
  int u = t ^ (row & 7);
  const float* p = &lds[row * 64 + u * 8];
  float4 a = *(const float4*)p;
  float4 b = *(const float4*)(p + 4);
  return bf16x8{(bf16)a.x, (bf16)a.y, (bf16)a.z, (bf16)a.w,
                (bf16)b.x, (bf16)b.y, (bf16)b.z, (bf16)b.w};
}

// ---------------------------------------------------------------------------
// qkvf: fused convert+GEMM. A (q/k/v) and W (weights) read as fp32 directly,
// staged via global_load_lds into fp32 LDS, cast to bf16 on fragment read.
// BM=128 x BN=64, BK=64, 4 waves (64x32 each). LDS 48KB -> 3 blocks/CU.
// Eliminates the convert kernel (96MB traffic) and its serialization.
// vt path: Vt store via LDS transpose T[64][136] (overlaid on smem).
// ---------------------------------------------------------------------------
template <typename TC>
__device__ __forceinline__ void gemm_f32(const float* __restrict__ A,
                                         const float* __restrict__ W,
                                         TC* __restrict__ C,
                                         bf16* __restrict__ vt, int K,
                                         int m0, int n0, float ascale) {
  constexpr int N = DMODEL;
  __shared__ alignas(16) float smem[128 * 64 + 64 * 64];  // As 32KB + Ws 16KB
  float* As = smem;
  float* Ws = smem + 128 * 64;

  const int tid = threadIdx.x;
  const int wave = tid >> 6;
  const int lane = tid & 63;
  const int quad = lane >> 4;
  const int l16 = lane & 15;
  const int wm = (wave >> 1) * 64;  // 0/64
  const int wn = (wave & 1) * 32;   // 0/32

  floatx4 acc[4][2] = {};

  for (int k0 = 0; k0 < K; k0 += 64) {
    stage_f32<8>(A + (size_t)m0 * K + k0, As, K, wave, lane);  // 128x64
    stage_f32<4>(W + (size_t)n0 * K + k0, Ws, K, wave, lane);  // 64x64
    __syncthreads();

#pragma unroll
    for (int kk = 0; kk < 2; ++kk) {
      bf16x8 af[4], bfv[2];
#pragma unroll
      for (int mi = 0; mi < 4; ++mi)
        af[mi] = fragf(As, wm + mi * 16 + l16, kk * 4 + quad);
#pragma unroll
      for (int ni = 0; ni < 2; ++ni)
        bfv[ni] = fragf(Ws, wn + ni * 16 + l16, kk * 4 + quad);
#pragma unroll
      for (int mi = 0; mi < 4; ++mi)
#pragma unroll
        for (int ni = 0; ni < 2; ++ni)
          acc[mi][ni] = MFMA16(af[mi], bfv[ni], acc[mi][ni]);
    }
    __syncthreads();
  }

  if (vt) {
    // transpose epilogue: acc -> T[col][row] (pad 136), then coalesced 16B
    // row-stores of Vt[d][s]. T = 64*136*2B = 17.4KB, overlaid on smem.
    bf16* T = (bf16*)smem;
#pragma unroll
    for (int mi = 0; mi < 4; ++mi)
#pragma unroll
      for (int ni = 0; ni < 2; ++ni) {
        int row = wm + mi * 16 + quad * 4;  // +r contiguous
        int col = wn + ni * 16 + l16;
        bf16x4 vvv = {(bf16)acc[mi][ni][0], (bf16)acc[mi][ni][1],
                      (bf16)acc[mi][ni][2], (bf16)acc[mi][ni][3]};
        *(bf16x4*)&T[col * 136 + row] = vvv;
      }
    __syncthreads();
    const int bb = m0 >> 11;
    const int sbase = (m0 & 2047) + l16 * 8;
#pragma unroll
    for (int jj = 0; jj < 4; ++jj) {
      int colv = wave * 16 + jj * 4 + quad;  // 0..63
      int gcol = n0 + colv;
      int h = gcol >> 6, d = gcol & 63;
      bf16x8 rowv = *(const bf16x8*)&T[colv * 136 + l16 * 8];
      *(bf16x8*)&vt[(size_t)((bb * NH + h) * DKH + d) * S_ + sbase] = rowv;
    }
  } else {
#pragma unroll
    for (int mi = 0; mi < 4; ++mi)
#pragma unroll
      for (int ni = 0; ni < 2; ++ni)
#pragma unroll
        for (int r = 0; r < 4; ++r) {
          int row = m0 + wm + mi * 16 + quad * 4 + r;
          int col = n0 + wn + ni * 16 + l16;
          C[(size_t)row * N + col] = (TC)(acc[mi][ni][r] * ascale);
        }
  }
}

// grid 1536 (3 GEMMs x 32 m-tiles x 16 n-tiles). bid&7 = XCD; each XCD owns
// m-rows [512*xcd, 512*xcd+512) of all three fp32 A matrices (4MB fp32,
// L2-resident across the 16 n-tile re-reads).
__global__ __launch_bounds__(256, 3) void qkvf_kernel(
    const float* __restrict__ q, const float* __restrict__ k,
    const float* __restrict__ v, const float* __restrict__ wq,
    const float* __restrict__ wk, const float* __restrict__ wv,
    bf16* __restrict__ Q, bf16* __restrict__ K, bf16* __restrict__ Vt) {
  const int bid = blockIdx.x;
  const int xcd = bid & 7;
  const int idx = bid >> 3;   // 0..191
  const int z = idx >> 6;     // 0..2
  const int rem = idx & 63;
  const int n = rem & 15;     // n-tile (64 cols)
  const int yslot = rem >> 4; // 0..3
  const int y = xcd * 4 + yslot;  // m-tile (128 rows)

  const float* A = (z == 0) ? q : (z == 1) ? k : v;
  const float* W = (z == 0) ? wq : (z == 1) ? wk : wv;
  bf16* C = (z == 0) ? Q : K;
  gemm_f32<bf16>(A, W, (z == 2) ? nullptr : C, (z == 2) ? Vt : nullptr,
                 DMODEL, y * 128, n * 64, (z == 0) ? CEXP : 1.0f);
}

// oprojf: A bf16 (attn output), W fp32 (wo, converted on fragment read).
// BM=64, BN=128, BK=64 -> grid 512 (2 blocks/CU active), LDS 40KB.
__global__ __launch_bounds__(256) void oprojf_kernel(
    const bf16* __restrict__ A, const float* __restrict__ W,
    float* __restrict__ C) {
  constexpr int K = DMODEL;
  constexpr int N = DMODEL;
  __shared__ alignas(16) float Ws[128 * 64];   // 32KB
  __shared__ alignas(16) bf16 As[64 * 64];     // 8KB

  const int bid = blockIdx.x;
  const int xcd = bid & 7;
  const int j = bid >> 3;
  const int n = j & 7;
  const int slot = j >> 3;
  const int mt = xcd * 8 + slot;
  const int m0 = mt * 64;
  const int n0 = n * 128;

  const int tid = threadIdx.x;
  const int wave = tid >> 6;
  const int lane = tid & 63;
  const int quad = lane >> 4;
  const int l16 = lane & 15;
  const int wm = (wave >> 1) * 32;
  const int wn = (wave & 1) * 64;

  floatx4 acc[2][4] = {};

  for (int k0 = 0; k0 < K; k0 += 64) {
#pragma unroll
    for (int i = 0; i < 2; ++i) {  // A 64x64 bf16
      int cb = (wave * 2 + i) * 64;
      int c = cb + lane;
      int r = c >> 3;
      int s = (c & 7) ^ (r & 7);
      load_lds16(&A[(size_t)(m0 + r) * K + k0 + s * 8], &As[cb * 8]);
    }
    stage_f32<8>(W + (size_t)n0 * K + k0, Ws, K, wave, lane);  // 128x64 f32
    __syncthreads();

#pragma unroll
    for (int kk = 0; kk < 2; ++kk) {
      bf16x8 af[2], bfv[4];
#pragma unroll
      for (int mi = 0; mi < 2; ++mi)
        af[mi] = frag64(As, wm + mi * 16 + l16, kk * 4 + quad);
#pragma unroll
      for (int ni = 0; ni < 4; ++ni)
        bfv[ni] = fragf(Ws, wn + ni * 16 + l16, kk * 4 + quad);
#pragma unroll
      for (int mi = 0; mi < 2; ++mi)
#pragma unroll
        for (int ni = 0; ni < 4; ++ni)
          acc[mi][ni] = MFMA16(af[mi], bfv[ni], acc[mi][ni]);
    }
    __syncthreads();
  }

#pragma unroll
  for (int mi = 0; mi < 2; ++mi)
#pragma unroll
    for (int ni = 0; ni < 4; ++ni)
#pragma unroll
      for (int r = 0; r < 4; ++r) {
        int row = m0 + wm + mi * 16 + quad * 4 + r;
        int col = n0 + wn + ni * 16 + l16;
        C[(size_t)row * N + col] = acc[mi][ni][r];
      }
}

// ---------------------------------------------------------------------------
// Causal flash attention v8 (best measured: 43.5-52us across sessions,
// cross-session noise dominant). UNCHANGED: stable reference. Balanced
// q-tile pairing (pr, 31-pr), hoisted shared ka/va fragments, 512 blocks x
// 256 threads, LDS 32.8KB dbuf (4 blocks/CU), 2-phase prefetch, setprio.
// ---------------------------------------------------------------------------
__device__ __forceinline__ void stage_kv(const bf16* __restrict__ K,
                                         const bf16* __restrict__ Vt,
                                         bf16* Ks, bf16* Vts, size_t baseQ,
                                         size_t baseV, int kt, int wave,
                                         int lane) {
#pragma unroll
  for (int i = 0; i < 2; ++i) {
    int cb = (wave * 2 + i) * 64;
    int c = cb + lane;
    int r = c >> 3;
    int s = (c & 7) ^ (r & 7);
    load_lds16(&K[baseQ + (size_t)(kt * 64 + r) * DMODEL + s * 8], &Ks[cb * 8]);
    load_lds16(&Vt[baseV + (size_t)r * S_ + kt * 64 + s * 8], &Vts[cb * 8]);
  }
}

template <bool DIAG>
__device__ __forceinline__ void softmax4(const floatx4 sa[4], bf16x4 pb[4],
                                         float lp[4], int quad, int qb) {
#pragma unroll
  for (int kg = 0; kg < 4; ++kg) {
    float pv[4];
#pragma unroll
    for (int r = 0; r < 4; ++r) {
      float s = sa[kg][r];
      if (DIAG) {
        int key = kg * 16 + quad * 4 + r;
        s = (key > qb) ? -3.0e38f : s;
      }
      float p = __builtin_amdgcn_exp2f(s);
      lp[kg] += p;
      pv[r] = p;
    }
    pb[kg] = bf16x4{(bf16)pv[0], (bf16)pv[1], (bf16)pv[2], (bf16)pv[3]};
  }
}

// single-tile step (H-only iterations and the final H diagonal)
template <bool DIAG>
__device__ __forceinline__ void attn_tile(const bf16* Ks, const bf16* Vts,
                                          const bf16x8 qf[2], floatx4 ot[4],
                                          float lp[4], int quad, int l16,
                                          int qb) {
  floatx4 sa[4] = {};
#pragma unroll
  for (int kk = 0; kk < 2; ++kk)
#pragma unroll
    for (int kg = 0; kg < 4; ++kg) {
      bf16x8 ka = frag64(Ks, kg * 16 + l16, kk * 4 + quad);
      sa[kg] = MFMA16(ka, qf[kk], sa[kg]);
    }
  bf16x4 pb[4];
  softmax4<DIAG>(sa, pb, lp, quad, qb);
#pragma unroll
  for (int kg = 0; kg < 4; ++kg)
#pragma unroll
    for (int di = 0; di < 4; ++di) {
      bf16x4 va = frag64h(Vts, di * 16 + l16, kg * 2 + (quad >> 1), quad & 1);
      ot[di] = MFMAK16(va, pb[kg], ot[di]);
    }
}

// paired step: one ka/va load feeds both tiles. LMODE: 1=L full, 2=L diag.
template <int LMODE>
__device__ __forceinline__ void pair_tile(const bf16* Ks, const bf16* Vts,
                                          const bf16x8 qfL[2],
                                          const bf16x8 qfH[2], floatx4 otL[4],
                                          floatx4 otH[4], float lpL[4],
                                          float lpH[4], int quad, int l16,
                                          int qb) {
  floatx4 saL[4] = {}, saH[4] = {};
#pragma unroll
  for (int kk = 0; kk < 2; ++kk)
#pragma unroll
    for (int kg = 0; kg < 4; ++kg) {
      bf16x8 ka = frag64(Ks, kg * 16 + l16, kk * 4 + quad);
      saL[kg] = MFMA16(ka, qfL[kk], saL[kg]);
      saH[kg] = MFMA16(ka, qfH[kk], saH[kg]);
    }
  bf16x4 pbL[4], pbH[4];
  if (LMODE == 1)
    softmax4<false>(saL, pbL, lpL, quad, qb);
  else
    softmax4<true>(saL, pbL, lpL, quad, qb);
  softmax4<false>(saH, pbH, lpH, quad, qb);
#pragma unroll
  for (int kg = 0; kg < 4; ++kg)
#pragma unroll
    for (int di = 0; di < 4; ++di) {
      bf16x4 va = frag64h(Vts, di * 16 + l16, kg * 2 + (quad >> 1), quad & 1);
      otL[di] = MFMAK16(va, pbL[kg], otL[di]);
      otH[di] = MFMAK16(va, pbH[kg], otH[di]);
    }
}

__global__ __launch_bounds__(256) void attn8_kernel(const bf16* __restrict__ Q,
                                                    const bf16* __restrict__ K,
                                                    const bf16* __restrict__ Vt,
                                                    bf16* __restrict__ O) {
  __shared__ alignas(16) bf16 Ks[2][64 * 64];
  __shared__ alignas(16) bf16 Vts[2][64 * 64];

  const int tid = threadIdx.x;
  const int wave = tid >> 6;
  const int lane = tid & 63;
  const int quad = lane >> 4;
  const int l16 = lane & 15;

  const int j = blockIdx.x;
  const int bh = j & 31;   // bid&7 = bh&7: heads spread across XCDs
  const int pr = j >> 5;   // 0..15: pair (pr, 31-pr) -> constant 33 units/block
  const int qtL = pr;
  const int qtH = 31 - pr;
  const int h = bh & 15;
  const int b = bh >> 4;
  const size_t baseQ = (size_t)b * S_ * DMODEL + (size_t)h * DKH;
  const size_t baseV = (size_t)bh * DKH * S_;

  // Q fragments in B-operand layout (lane=q, k=quad*8+j), pre-scaled by CEXP
  bf16x8 qfL[2], qfH[2];
#pragma unroll
  for (int kk = 0; kk < 2; ++kk) {
    qfL[kk] = *(const bf16x8*)&Q[baseQ +
        (size_t)(qtL * 64 + wave * 16 + l16) * DMODEL + kk * 32 + quad * 8];
    qfH[kk] = *(const bf16x8*)&Q[baseQ +
        (size_t)(qtH * 64 + wave * 16 + l16) * DMODEL + kk * 32 + quad * 8];
  }

  floatx4 otL[4] = {}, otH[4] = {};  // O^T accum: (d=di*16+quad*4+r, q=l16)
  float lpL[4] = {}, lpH[4] = {};    // per-lane partial l (by key-group)
  const int qb = wave * 16 + l16;    // q index within each 64-row tile

  stage_kv(K, Vt, Ks[0], Vts[0], baseQ, baseV, 0, wave, lane);
  __syncthreads();  // drains vmcnt(0)

  for (int kt = 0; kt < qtH; ++kt) {
    const int cur = kt & 1;
    // issue next tile's staging first: latency hides under compute
    stage_kv(K, Vt, Ks[cur ^ 1], Vts[cur ^ 1], baseQ, baseV, kt + 1, wave, lane);

    __builtin_amdgcn_s_setprio(1);
    if (kt < qtL)
      pair_tile<1>(Ks[cur], Vts[cur], qfL, qfH, otL, otH, lpL, lpH, quad, l16, qb);
    else if (kt == qtL)
      pair_tile<2>(Ks[cur], Vts[cur], qfL, qfH, otL, otH, lpL, lpH, quad, l16, qb);
    else
      attn_tile<false>(Ks[cur], Vts[cur], qfH, otH, lpH, quad, l16, qb);
    __builtin_amdgcn_s_setprio(0);

    __syncthreads();  // next buffer ready, this one free
  }
  {  // last tile: diagonal of the high q-tile (qtL < qtH always since pr<16)
    const int cur = qtH & 1;
    attn_tile<true>(Ks[cur], Vts[cur], qfH, otH, lpH, quad, l16, qb);
  }

  // l: per-lane sum, then reduce across the 4 quads sharing q=l16
  float lL = (lpL[0] + lpL[1]) + (lpL[2] + lpL[3]);
  lL += __shfl_xor(lL, 16, 64);
  lL += __shfl_xor(lL, 32, 64);
  float lH = (lpH[0] + lpH[1]) + (lpH[2] + lpH[3]);
  lH += __shfl_xor(lH, 16, 64);
  lH += __shfl_xor(lH, 32, 64);
  const float invL = 1.0f / lL;
  const float invH = 1.0f / lH;

  // store O^T -> O[q][d] (2B scattered; epilogue-only)
  const size_t orowL = baseQ + (size_t)(qtL * 64 + wave * 16 + l16) * DMODEL;
  const size_t orowH = baseQ + (size_t)(qtH * 64 + wave * 16 + l16) * DMODEL;
#pragma unroll
  for (int di = 0; di < 4; ++di)
#pragma unroll
    for (int r = 0; r < 4; ++r) {
      O[orowL + di * 16 + quad * 4 + r] = (bf16)(otL[di][r] * invL);
      O[orowH + di * 16 + quad * 4 + r] = (bf16)(otH[di][r] * invH);
    }
}

// ---------------------------------------------------------------------------
// 3-dispatch pipeline: qkvf (fused fp32 convert+GEMM) -> attn8 -> oprojf.
// Workspace: 32MB (Qp/Kp/VtG/AO). The old convert kernel (96MB of HBM
// traffic + one serialization point) is eliminated.
// ---------------------------------------------------------------------------
extern "C" void kernel_launch(void* const* d_in, const int* in_sizes, int n_in,
                              void* d_out, int out_size, void* d_ws,
                              size_t ws_size, hipStream_t stream) {
  const float* q = (const float*)d_in[0];
  const float* k = (const float*)d_in[1];
  const float* v = (const float*)d_in[2];
  // d_in[3] = causal mask: static tril, computed analytically in-kernel
  const float* wq = (const float*)d_in[4];
  const float* wk = (const float*)d_in[5];
  const float* wv = (const float*)d_in[6];
  const float* wo = (const float*)d_in[7];
  float* out = (float*)d_out;

  const size_t MB = 1024 * 1024;
  char* base = (char*)d_ws;
  bf16* Qp = (bf16*)(base);
  bf16* Kp = (bf16*)(base + 8 * MB);
  bf16* VtG = (bf16*)(base + 16 * MB);
  bf16* AO = (bf16*)(base + 24 * MB);

  qkvf_kernel<<<dim3(1536), 256, 0, stream>>>(q, k, v, wq, wk, wv, Qp, Kp, VtG);
  attn8_kernel<<<dim3(512), 256, 0, stream>>>(Qp, Kp, VtG, AO);
  oprojf_kernel<<<dim3(512), 256, 0, stream>>>(AO, wo, out);
}

// Round 9
// 207.949 us; speedup vs baseline: 1.9026x; 1.9026x over previous
//
#include <hip/hip_runtime.h>
#include <cstdint>
#include <cstddef>

typedef __bf16 bf16;
typedef __attribute__((ext_vector_type(4))) __bf16 bf16x4;
typedef __attribute__((ext_vector_type(8))) __bf16 bf16x8;
typedef __attribute__((ext_vector_type(4))) float floatx4;
typedef __attribute__((ext_vector_type(4))) short short4v;

#define MFMA16(a, b, c) __builtin_amdgcn_mfma_f32_16x16x32_bf16((a), (b), (c), 0, 0, 0)

// K=16 bf16 MFMA: A[m=l16][k=quad*4+j], B[n=l16][k=quad*4+j], C row=quad*4+r col=l16
__device__ __forceinline__ floatx4 MFMAK16(bf16x4 a, bf16x4 b, floatx4 c) {
#if __has_builtin(__builtin_amdgcn_mfma_f32_16x16x16bf16_1k)
  return __builtin_amdgcn_mfma_f32_16x16x16bf16_1k(
      __builtin_bit_cast(short4v, a), __builtin_bit_cast(short4v, b), c, 0, 0, 0);
#else
  floatx4 d;
  asm("v_mfma_f32_16x16x16_bf16 %0, %1, %2, %3"
      : "=v"(d)
      : "v"(a), "v"(b), "v"(c));
  return d;
#endif
}

constexpr int DMODEL = 1024;
constexpr int NH = 16;
constexpr int DKH = 64;
constexpr int B_ = 2;
constexpr int S_ = 2048;
constexpr int MTOT = B_ * S_;  // 4096
constexpr float CEXP = 0.125f * 1.44269504f;  // log2(e)/sqrt(64), folded into Q

// async global->LDS, 16B/lane; LDS dest = wave-uniform base + lane*16
__device__ __forceinline__ void load_lds16(const void* g, void* l) {
  __builtin_amdgcn_global_load_lds(
      (const __attribute__((address_space(1))) uint32_t*)g,
      (__attribute__((address_space(3))) uint32_t*)l, 16, 0, 0);
}

// ---------------------------------------------------------------------------
// Swizzled LDS tiles: 64-col bf16 rows (8 x 16B chunks/row), chunk swizzle
// s = c ^ (row & 7); reads via frag64 (b128) / frag64h (b64) -> <=2-way banks.
// ---------------------------------------------------------------------------
__device__ __forceinline__ bf16x8 frag64(const bf16* lds, int row, int p) {
  int s = p ^ (row & 7);
  return *(const bf16x8*)&lds[row * 64 + s * 8];
}
// 8B read at global chunk p (16B units), sub-half h (0/1)
__device__ __forceinline__ bf16x4 frag64h(const bf16* lds, int row, int p, int h) {
  int s = p ^ (row & 7);
  return *(const bf16x4*)&lds[row * 64 + s * 8 + h * 4];
}

// 32-col variants (BK=32 fallback path)
__device__ __forceinline__ void stage32_bf16(const bf16* __restrict__ src,
                                             bf16* lds, int wave, int lane,
                                             int ldg) {
#pragma unroll
  for (int i = 0; i < 2; ++i) {
    int cb = (wave * 2 + i) * 64;
    int c = cb + lane;
    int r = c >> 2;
    int s = (c & 3) ^ ((r >> 1) & 3);
    load_lds16(&src[(size_t)r * ldg + s * 8], &lds[cb * 8]);
  }
}
__device__ __forceinline__ bf16x8 frag32_bf16(const bf16* lds, int row,
                                              int quad) {
  int s = quad ^ ((row >> 1) & 3);
  return *(const bf16x8*)&lds[row * 32 + s * 8];
}
__device__ __forceinline__ void stage32_f32(const float* __restrict__ src,
                                            float* lds, int wave, int lane,
                                            int ldg) {
#pragma unroll
  for (int i = 0; i < 4; ++i) {
    int cb = (wave * 4 + i) * 64;
    int c = cb + lane;
    int r = c >> 3;
    int s = (c & 7) ^ (r & 7);
    load_lds16(&src[(size_t)r * ldg + s * 4], &lds[cb * 4]);
  }
}
__device__ __forceinline__ bf16x8 frag32_f32(const float* lds, int row,
                                             int quad) {
  int s1 = (2 * quad) ^ (row & 7);
  int s2 = (2 * quad + 1) ^ (row & 7);
  float4 a = *(const float4*)&lds[row * 32 + s1 * 4];
  float4 b = *(const float4*)&lds[row * 32 + s2 * 4];
  bf16x8 h = {(bf16)a.x, (bf16)a.y, (bf16)a.z, (bf16)a.w,
              (bf16)b.x, (bf16)b.y, (bf16)b.z, (bf16)b.w};
  return h;
}

// ---------------------------------------------------------------------------
// fp32 -> bf16 bulk convert (fast path only). Flat exact-size grid: 8192
// blocks (3x2048 for q/k/v + 4x512 for weights). NOT fused into the GEMMs:
// R8 measured that fp32 A-panels (2x footprint) thrash the 4MB per-XCD L2
// under the 16x n-tile re-reads (FETCH 12->90MB, 208us). Pre-converting to
// bf16 is what keeps the GEMM's A-panel L2-resident.
// ---------------------------------------------------------------------------
__global__ __launch_bounds__(256) void convert_kernel(
    const float* __restrict__ q, const float* __restrict__ k,
    const float* __restrict__ v, const float* __restrict__ wq,
    const float* __restrict__ wk, const float* __restrict__ wv,
    const float* __restrict__ wo, bf16* __restrict__ qb, bf16* __restrict__ kb,
    bf16* __restrict__ vb, bf16* __restrict__ wqb, bf16* __restrict__ wkb,
    bf16* __restrict__ wvb, bf16* __restrict__ wob) {
  const int bid = blockIdx.x;
  int seg, rel;
  if (bid < 6144) {
    seg = bid >> 11;        // 0..2 : q,k,v (2048 blocks each)
    rel = bid & 2047;
  } else {
    int t = bid - 6144;
    seg = 3 + (t >> 9);     // 3..6 : wq,wk,wv,wo (512 blocks each)
    rel = t & 511;
  }
  const float* src;
  bf16* dst;
  switch (seg) {
    case 0: src = q;  dst = qb;  break;
    case 1: src = k;  dst = kb;  break;
    case 2: src = v;  dst = vb;  break;
    case 3: src = wq; dst = wqb; break;
    case 4: src = wk; dst = wkb; break;
    case 5: src = wv; dst = wvb; break;
    default: src = wo; dst = wob; break;
  }
  size_t idx = ((size_t)rel * 256 + threadIdx.x) * 8;
  float4 f0 = *(const float4*)&src[idx];
  float4 f1 = *(const float4*)&src[idx + 4];
  bf16x8 h = {(bf16)f0.x, (bf16)f0.y, (bf16)f0.z, (bf16)f0.w,
              (bf16)f1.x, (bf16)f1.y, (bf16)f1.z, (bf16)f1.w};
  *(bf16x8*)&dst[idx] = h;
}

// ---------------------------------------------------------------------------
// gemm64: bf16 GEMM, 128x128 tile, BK=64, 4 waves. C-store scaled by ascale.
// vt path: Vt store via LDS transpose -> coalesced 16B stores. smem overlay:
// As/Bs staging (32KB) and T[128][136] transpose buffer share one allocation.
// This is the config present in the session-best totals (R4/R5).
// ---------------------------------------------------------------------------
template <typename TC>
__device__ __forceinline__ void gemm64(const bf16* __restrict__ A,
                                       const bf16* __restrict__ W,
                                       TC* __restrict__ C,
                                       bf16* __restrict__ vt, int K,
                                       int m0, int n0, float ascale) {
  constexpr int N = DMODEL;
  __shared__ alignas(16) bf16 smem[128 * 136];  // max(As+Bs, T)
  bf16* As = smem;            // 128*64
  bf16* Bs = smem + 128 * 64; // 128*64

  const int tid = threadIdx.x;
  const int wave = tid >> 6;
  const int lane = tid & 63;
  const int quad = lane >> 4;
  const int l16 = lane & 15;
  const int wm = (wave >> 1) * 64;
  const int wn = (wave & 1) * 64;

  floatx4 acc[4][4] = {};

  for (int k0 = 0; k0 < K; k0 += 64) {
#pragma unroll
    for (int i = 0; i < 4; ++i) {
      int cb = (wave * 4 + i) * 64;
      int c = cb + lane;
      int r = c >> 3;
      int s = (c & 7) ^ (r & 7);
      load_lds16(&A[(size_t)(m0 + r) * K + k0 + s * 8], &As[cb * 8]);
      load_lds16(&W[(size_t)(n0 + r) * K + k0 + s * 8], &Bs[cb * 8]);
    }
    __syncthreads();

#pragma unroll
    for (int kk = 0; kk < 2; ++kk) {
      bf16x8 af[4], bfv[4];
#pragma unroll
      for (int mi = 0; mi < 4; ++mi)
        af[mi] = frag64(As, wm + mi * 16 + l16, kk * 4 + quad);
#pragma unroll
      for (int ni = 0; ni < 4; ++ni)
        bfv[ni] = frag64(Bs, wn + ni * 16 + l16, kk * 4 + quad);
#pragma unroll
      for (int mi = 0; mi < 4; ++mi)
#pragma unroll
        for (int ni = 0; ni < 4; ++ni)
          acc[mi][ni] = MFMA16(af[mi], bfv[ni], acc[mi][ni]);
    }
    __syncthreads();
  }

  if (vt) {
    // transpose epilogue: acc -> T[col][row] (pad 136 -> ~2-way banks),
    // then coalesced 16B row-stores of Vt[d][s].
    bf16* T = smem;
#pragma unroll
    for (int mi = 0; mi < 4; ++mi)
#pragma unroll
      for (int ni = 0; ni < 4; ++ni) {
        int row = wm + mi * 16 + quad * 4;      // +r contiguous
        int col = wn + ni * 16 + l16;
        bf16x4 vvv = {(bf16)acc[mi][ni][0], (bf16)acc[mi][ni][1],
                      (bf16)acc[mi][ni][2], (bf16)acc[mi][ni][3]};
        *(bf16x4*)&T[col * 136 + row] = vvv;
      }
    __syncthreads();
    const int bb = m0 >> 11;
    const int sbase = (m0 & 2047) + l16 * 8;
#pragma unroll
    for (int jj = 0; jj < 8; ++jj) {
      int colv = wave * 32 + jj * 4 + quad;
      int gcol = n0 + colv;
      int h = gcol >> 6, d = gcol & 63;
      bf16x8 rowv = *(const bf16x8*)&T[colv * 136 + l16 * 8];
      *(bf16x8*)&vt[(size_t)((bb * NH + h) * DKH + d) * S_ + sbase] = rowv;
    }
  } else {
#pragma unroll
    for (int mi = 0; mi < 4; ++mi)
#pragma unroll
      for (int ni = 0; ni < 4; ++ni)
#pragma unroll
        for (int r = 0; r < 4; ++r) {
          int row = m0 + wm + mi * 16 + quad * 4 + r;
          int col = n0 + wn + ni * 16 + l16;
          C[(size_t)row * N + col] = (TC)(acc[mi][ni][r] * ascale);
        }
  }
}

// qkv fast path: flat grid 768, XCD row-ownership (bid&7 = XCD round-robin).
// bf16 inputs keep the per-XCD A-panel at 3MB -> L2-resident across the 8
// n-tile re-reads (the R8 fp32-fused variant doubled this and thrashed).
__global__ __launch_bounds__(256, 3) void qkv64_kernel(
    const bf16* __restrict__ q, const bf16* __restrict__ k,
    const bf16* __restrict__ v, const bf16* __restrict__ wq,
    const bf16* __restrict__ wk, const bf16* __restrict__ wv,
    bf16* __restrict__ Q, bf16* __restrict__ K, bf16* __restrict__ Vt) {
  const int bid = blockIdx.x;
  const int xcd = bid & 7;
  const int j = bid >> 3;
  const int n = j & 7;
  const int rowslot = j >> 3;
  const int p = xcd * 12 + rowslot;
  const int z = p >> 5;
  const int y = p & 31;

  const bf16* A = (z == 0) ? q : (z == 1) ? k : v;
  const bf16* W = (z == 0) ? wq : (z == 1) ? wk : wv;
  bf16* C = (z == 0) ? Q : K;
  gemm64<bf16>(A, W, (z == 2) ? nullptr : C, (z == 2) ? Vt : nullptr,
               DMODEL, y * 128, n * 128, (z == 0) ? CEXP : 1.0f);
}

// oproj fast path: BM=64, BN=128, BK=64 -> grid 512 (2 blocks/CU), LDS 24KB.
__global__ __launch_bounds__(256) void oproj64_kernel(
    const bf16* __restrict__ A, const bf16* __restrict__ W,
    float* __restrict__ C) {
  constexpr int K = DMODEL;
  constexpr int N = DMODEL;
  __shared__ alignas(16) bf16 As[64 * 64];
  __shared__ alignas(16) bf16 Bs[128 * 64];

  const int bid = blockIdx.x;
  const int xcd = bid & 7;
  const int j = bid >> 3;
  const int n = j & 7;
  const int slot = j >> 3;
  const int mt = xcd * 8 + slot;
  const int m0 = mt * 64;
  const int n0 = n * 128;

  const int tid = threadIdx.x;
  const int wave = tid >> 6;
  const int lane = tid & 63;
  const int quad = lane >> 4;
  const int l16 = lane & 15;
  const int wm = (wave >> 1) * 32;
  const int wn = (wave & 1) * 64;

  floatx4 acc[2][4] = {};

  for (int k0 = 0; k0 < K; k0 += 64) {
#pragma unroll
    for (int i = 0; i < 2; ++i) {
      int cb = (wave * 2 + i) * 64;
      int c = cb + lane;
      int r = c >> 3;
      int s = (c & 7) ^ (r & 7);
      load_lds16(&A[(size_t)(m0 + r) * K + k0 + s * 8], &As[cb * 8]);
    }
#pragma unroll
    for (int i = 0; i < 4; ++i) {
      int cb = (wave * 4 + i) * 64;
      int c = cb + lane;
      int r = c >> 3;
      int s = (c & 7) ^ (r & 7);
      load_lds16(&W[(size_t)(n0 + r) * K + k0 + s * 8], &Bs[cb * 8]);
    }
    __syncthreads();

#pragma unroll
    for (int kk = 0; kk < 2; ++kk) {
      bf16x8 af[2], bfv[4];
#pragma unroll
      for (int mi = 0; mi < 2; ++mi)
        af[mi] = frag64(As, wm + mi * 16 + l16, kk * 4 + quad);
#pragma unroll
      for (int ni = 0; ni < 4; ++ni)
        bfv[ni] = frag64(Bs, wn + ni * 16 + l16, kk * 4 + quad);
#pragma unroll
      for (int mi = 0; mi < 2; ++mi)
#pragma unroll
        for (int ni = 0; ni < 4; ++ni)
          acc[mi][ni] = MFMA16(af[mi], bfv[ni], acc[mi][ni]);
    }
    __syncthreads();
  }

#pragma unroll
  for (int mi = 0; mi < 2; ++mi)
#pragma unroll
    for (int ni = 0; ni < 4; ++ni)
#pragma unroll
      for (int r = 0; r < 4; ++r) {
        int row = m0 + wm + mi * 16 + quad * 4 + r;
        int col = n0 + wn + ni * 16 + l16;
        C[(size_t)row * N + col] = acc[mi][ni][r];
      }
}

// ---------------------------------------------------------------------------
// Fallback (ws < 64MB): fp32-input GEMM, BK=32. ascale folds CEXP into Q.
// ---------------------------------------------------------------------------
template <typename TA, typename TW, typename TC>
__device__ __forceinline__ void gemm_core(const TA* __restrict__ A,
                                          const TW* __restrict__ W,
                                          TC* __restrict__ C,
                                          bf16* __restrict__ vt, int K,
                                          int m0, int n0, float ascale) {
  constexpr int N = DMODEL;
  __shared__ alignas(16) char smem[128 * 32 * (sizeof(TA) + sizeof(TW))];
  TA* As = (TA*)smem;
  TW* Bs = (TW*)(smem + 128 * 32 * sizeof(TA));

  const int tid = threadIdx.x;
  const int wave = tid >> 6;
  const int lane = tid & 63;
  const int quad = lane >> 4;
  const int l16 = lane & 15;
  const int wm = (wave >> 1) * 64;
  const int wn = (wave & 1) * 64;

  floatx4 acc[4][4] = {};

  for (int k0 = 0; k0 < K; k0 += 32) {
    if constexpr (sizeof(TA) == 2)
      stage32_bf16((const bf16*)A + (size_t)m0 * K + k0, (bf16*)As, wave, lane, K);
    else
      stage32_f32((const float*)A + (size_t)m0 * K + k0, (float*)As, wave, lane, K);
    if constexpr (sizeof(TW) == 2)
      stage32_bf16((const bf16*)W + (size_t)n0 * K + k0, (bf16*)Bs, wave, lane, K);
    else
      stage32_f32((const float*)W + (size_t)n0 * K + k0, (float*)Bs, wave, lane, K);
    __syncthreads();

    bf16x8 af[4], bfv[4];
#pragma unroll
    for (int mi = 0; mi < 4; ++mi) {
      if constexpr (sizeof(TA) == 2)
        af[mi] = frag32_bf16((const bf16*)As, wm + mi * 16 + l16, quad);
      else
        af[mi] = frag32_f32((const float*)As, wm + mi * 16 + l16, quad);
    }
#pragma unroll
    for (int ni = 0; ni < 4; ++ni) {
      if constexpr (sizeof(TW) == 2)
        bfv[ni] = frag32_bf16((const bf16*)Bs, wn + ni * 16 + l16, quad);
      else
        bfv[ni] = frag32_f32((const float*)Bs, wn + ni * 16 + l16, quad);
    }
#pragma unroll
    for (int mi = 0; mi < 4; ++mi)
#pragma unroll
      for (int ni = 0; ni < 4; ++ni)
        acc[mi][ni] = MFMA16(af[mi], bfv[ni], acc[mi][ni]);
    __syncthreads();
  }

  if (vt) {
#pragma unroll
    for (int mi = 0; mi < 4; ++mi)
#pragma unroll
      for (int ni = 0; ni < 4; ++ni)
#pragma unroll
        for (int r = 0; r < 4; ++r) {
          int row = m0 + wm + mi * 16 + quad * 4 + r;
          int col = n0 + wn + ni * 16 + l16;
          int bb = row >> 11, s = row & 2047;
          int h = col >> 6, d = col & 63;
          vt[(size_t)((bb * NH + h) * DKH + d) * S_ + s] = (bf16)acc[mi][ni][r];
        }
  } else {
#pragma unroll
    for (int mi = 0; mi < 4; ++mi)
#pragma unroll
      for (int ni = 0; ni < 4; ++ni)
#pragma unroll
        for (int r = 0; r < 4; ++r) {
          int row = m0 + wm + mi * 16 + quad * 4 + r;
          int col = n0 + wn + ni * 16 + l16;
          C[(size_t)row * N + col] = (TC)(acc[mi][ni][r] * ascale);
        }
  }
}

__global__ __launch_bounds__(256) void qkv_f32_kernel(
    const float* __restrict__ q, const float* __restrict__ k,
    const float* __restrict__ v, const float* __restrict__ wq,
    const float* __restrict__ wk, const float* __restrict__ wv,
    bf16* __restrict__ Q, bf16* __restrict__ K, bf16* __restrict__ Vt) {
  const int bid = blockIdx.x;
  const int xcd = bid & 7;
  const int j = bid >> 3;
  const int n = j & 7;
  const int rowslot = j >> 3;
  const int p = xcd * 12 + rowslot;
  const int z = p >> 5;
  const int y = p & 31;
  const float* A = (z == 0) ? q : (z == 1) ? k : v;
  const float* W = (z == 0) ? wq : (z == 1) ? wk : wv;
  bf16* C = (z == 0) ? Q : K;
  gemm_core<float, float, bf16>(A, W, (z == 2) ? nullptr : C,
                                (z == 2) ? Vt : nullptr, DMODEL, y * 128,
                                n * 128, (z == 0) ? CEXP : 1.0f);
}

__global__ __launch_bounds__(256) void oproj_f32_kernel(
    const bf16* __restrict__ A, const float* __restrict__ W,
    float* __restrict__ C) {
  const int bid = blockIdx.x;
  const int xcd = bid & 7;
  const int j = bid >> 3;
  const int n = j & 7;
  const int rowslot = j >> 3;
  const int y = xcd * 4 + rowslot;
  gemm_core<bf16, float, float>(A, W, C, nullptr, DMODEL, y * 128, n * 128,
                                1.0f);
}

// ---------------------------------------------------------------------------
// Causal flash attention v8 (best-measured attn across 7 structures:
// 43.5-45.5us typical). Balanced q-tile pairing (pr, 31-pr), hoisted shared
// ka/va fragments feeding both tiles, 512 blocks x 256 threads (4 waves),
// LDS 32.8KB dbuf, 2-phase prefetch, setprio around compute. UNCHANGED.
// ---------------------------------------------------------------------------
__device__ __forceinline__ void stage_kv(const bf16* __restrict__ K,
                                         const bf16* __restrict__ Vt,
                                         bf16* Ks, bf16* Vts, size_t baseQ,
                                         size_t baseV, int kt, int wave,
                                         int lane) {
#pragma unroll
  for (int i = 0; i < 2; ++i) {
    int cb = (wave * 2 + i) * 64;
    int c = cb + lane;
    int r = c >> 3;
    int s = (c & 7) ^ (r & 7);
    load_lds16(&K[baseQ + (size_t)(kt * 64 + r) * DMODEL + s * 8], &Ks[cb * 8]);
    load_lds16(&Vt[baseV + (size_t)r * S_ + kt * 64 + s * 8], &Vts[cb * 8]);
  }
}

template <bool DIAG>
__device__ __forceinline__ void softmax4(const floatx4 sa[4], bf16x4 pb[4],
                                         float lp[4], int quad, int qb) {
#pragma unroll
  for (int kg = 0; kg < 4; ++kg) {
    float pv[4];
#pragma unroll
    for (int r = 0; r < 4; ++r) {
      float s = sa[kg][r];
      if (DIAG) {
        int key = kg * 16 + quad * 4 + r;
        s = (key > qb) ? -3.0e38f : s;
      }
      float p = __builtin_amdgcn_exp2f(s);
      lp[kg] += p;
      pv[r] = p;
    }
    pb[kg] = bf16x4{(bf16)pv[0], (bf16)pv[1], (bf16)pv[2], (bf16)pv[3]};
  }
}

// single-tile step (H-only iterations and the final H diagonal)
template <bool DIAG>
__device__ __forceinline__ void attn_tile(const bf16* Ks, const bf16* Vts,
                                          const bf16x8 qf[2], floatx4 ot[4],
                                          float lp[4], int quad, int l16,
                                          int qb) {
  floatx4 sa[4] = {};
#pragma unroll
  for (int kk = 0; kk < 2; ++kk)
#pragma unroll
    for (int kg = 0; kg < 4; ++kg) {
      bf16x8 ka = frag64(Ks, kg * 16 + l16, kk * 4 + quad);
      sa[kg] = MFMA16(ka, qf[kk], sa[kg]);
    }
  bf16x4 pb[4];
  softmax4<DIAG>(sa, pb, lp, quad, qb);
#pragma unroll
  for (int kg = 0; kg < 4; ++kg)
#pragma unroll
    for (int di = 0; di < 4; ++di) {
      bf16x4 va = frag64h(Vts, di * 16 + l16, kg * 2 + (quad >> 1), quad & 1);
      ot[di] = MFMAK16(va, pb[kg], ot[di]);
    }
}

// paired step: one ka/va load feeds both tiles. LMODE: 1=L full, 2=L diag.
template <int LMODE>
__device__ __forceinline__ void pair_tile(const bf16* Ks, const bf16* Vts,
                                          const bf16x8 qfL[2],
                                          const bf16x8 qfH[2], floatx4 otL[4],
                                          floatx4 otH[4], float lpL[4],
                                          float lpH[4], int quad, int l16,
                                          int qb) {
  floatx4 saL[4] = {}, saH[4] = {};
#pragma unroll
  for (int kk = 0; kk < 2; ++kk)
#pragma unroll
    for (int kg = 0; kg < 4; ++kg) {
      bf16x8 ka = frag64(Ks, kg * 16 + l16, kk * 4 + quad);
      saL[kg] = MFMA16(ka, qfL[kk], saL[kg]);
      saH[kg] = MFMA16(ka, qfH[kk], saH[kg]);
    }
  bf16x4 pbL[4], pbH[4];
  if (LMODE == 1)
    softmax4<false>(saL, pbL, lpL, quad, qb);
  else
    softmax4<true>(saL, pbL, lpL, quad, qb);
  softmax4<false>(saH, pbH, lpH, quad, qb);
#pragma unroll
  for (int kg = 0; kg < 4; ++kg)
#pragma unroll
    for (int di = 0; di < 4; ++di) {
      bf16x4 va = frag64h(Vts, di * 16 + l16, kg * 2 + (quad >> 1), quad & 1);
      otL[di] = MFMAK16(va, pbL[kg], otL[di]);
      otH[di] = MFMAK16(va, pbH[kg], otH[di]);
    }
}

__global__ __launch_bounds__(256) void attn8_kernel(const bf16* __restrict__ Q,
                                                    const bf16* __restrict__ K,
                                                    const bf16* __restrict__ Vt,
                                                    bf16* __restrict__ O) {
  __shared__ alignas(16) bf16 Ks[2][64 * 64];
  __shared__ alignas(16) bf16 Vts[2][64 * 64];

  const int tid = threadIdx.x;
  const int wave = tid >> 6;
  const int lane = tid & 63;
  const int quad = lane >> 4;
  const int l16 = lane & 15;

  const int j = blockIdx.x;
  const int bh = j & 31;   // bid&7 = bh&7: heads spread across XCDs
  const int pr = j >> 5;   // 0..15: pair (pr, 31-pr) -> constant 33 units/block
  const int qtL = pr;
  const int qtH = 31 - pr;
  const int h = bh & 15;
  const int b = bh >> 4;
  const size_t baseQ = (size_t)b * S_ * DMODEL + (size_t)h * DKH;
  const size_t baseV = (size_t)bh * DKH * S_;

  // Q fragments in B-operand layout (lane=q, k=quad*8+j), pre-scaled by CEXP
  bf16x8 qfL[2], qfH[2];
#pragma unroll
  for (int kk = 0; kk < 2; ++kk) {
    qfL[kk] = *(const bf16x8*)&Q[baseQ +
        (size_t)(qtL * 64 + wave * 16 + l16) * DMODEL + kk * 32 + quad * 8];
    qfH[kk] = *(const bf16x8*)&Q[baseQ +
        (size_t)(qtH * 64 + wave * 16 + l16) * DMODEL + kk * 32 + quad * 8];
  }

  floatx4 otL[4] = {}, otH[4] = {};  // O^T accum: (d=di*16+quad*4+r, q=l16)
  float lpL[4] = {}, lpH[4] = {};    // per-lane partial l (by key-group)
  const int qb = wave * 16 + l16;    // q index within each 64-row tile

  stage_kv(K, Vt, Ks[0], Vts[0], baseQ, baseV, 0, wave, lane);
  __syncthreads();  // drains vmcnt(0)

  for (int kt = 0; kt < qtH; ++kt) {
    const int cur = kt & 1;
    // issue next tile's staging first: latency hides under compute
    stage_kv(K, Vt, Ks[cur ^ 1], Vts[cur ^ 1], baseQ, baseV, kt + 1, wave, lane);

    __builtin_amdgcn_s_setprio(1);
    if (kt < qtL)
      pair_tile<1>(Ks[cur], Vts[cur], qfL, qfH, otL, otH, lpL, lpH, quad, l16, qb);
    else if (kt == qtL)
      pair_tile<2>(Ks[cur], Vts[cur], qfL, qfH, otL, otH, lpL, lpH, quad, l16, qb);
    else
      attn_tile<false>(Ks[cur], Vts[cur], qfH, otH, lpH, quad, l16, qb);
    __builtin_amdgcn_s_setprio(0);

    __syncthreads();  // next buffer ready, this one free
  }
  {  // last tile: diagonal of the high q-tile (qtL < qtH always since pr<16)
    const int cur = qtH & 1;
    attn_tile<true>(Ks[cur], Vts[cur], qfH, otH, lpH, quad, l16, qb);
  }

  // l: per-lane sum, then reduce across the 4 quads sharing q=l16
  float lL = (lpL[0] + lpL[1]) + (lpL[2] + lpL[3]);
  lL += __shfl_xor(lL, 16, 64);
  lL += __shfl_xor(lL, 32, 64);
  float lH = (lpH[0] + lpH[1]) + (lpH[2] + lpH[3]);
  lH += __shfl_xor(lH, 16, 64);
  lH += __shfl_xor(lH, 32, 64);
  const float invL = 1.0f / lL;
  const float invH = 1.0f / lH;

  // store O^T -> O[q][d] (2B scattered; epilogue-only)
  const size_t orowL = baseQ + (size_t)(qtL * 64 + wave * 16 + l16) * DMODEL;
  const size_t orowH = baseQ + (size_t)(qtH * 64 + wave * 16 + l16) * DMODEL;
#pragma unroll
  for (int di = 0; di < 4; ++di)
#pragma unroll
    for (int r = 0; r < 4; ++r) {
      O[orowL + di * 16 + quad * 4 + r] = (bf16)(otL[di][r] * invL);
      O[orowH + di * 16 + quad * 4 + r] = (bf16)(otH[di][r] * invH);
    }
}

// ---------------------------------------------------------------------------
extern "C" void kernel_launch(void* const* d_in, const int* in_sizes, int n_in,
                              void* d_out, int out_size, void* d_ws,
                              size_t ws_size, hipStream_t stream) {
  const float* q = (const float*)d_in[0];
  const float* k = (const float*)d_in[1];
  const float* v = (const float*)d_in[2];
  // d_in[3] = causal mask: static tril, computed analytically in-kernel
  const float* wq = (const float*)d_in[4];
  const float* wk = (const float*)d_in[5];
  const float* wv = (const float*)d_in[6];
  const float* wo = (const float*)d_in[7];
  float* out = (float*)d_out;

  const size_t MB = 1024 * 1024;
  char* base = (char*)d_ws;
  bf16* Qp = (bf16*)(base);
  bf16* Kp = (bf16*)(base + 8 * MB);
  bf16* VtG = (bf16*)(base + 16 * MB);
  bf16* AO = (bf16*)(base + 24 * MB);

  if (ws_size >= 64 * MB) {
    bf16* qb = (bf16*)(base + 32 * MB);
    bf16* kb = (bf16*)(base + 40 * MB);
    bf16* vb = (bf16*)(base + 48 * MB);
    bf16* wqb = (bf16*)(base + 56 * MB);
    bf16* wkb = (bf16*)(base + 58 * MB);
    bf16* wvb = (bf16*)(base + 60 * MB);
    bf16* wob = (bf16*)(base + 62 * MB);
    convert_kernel<<<dim3(8192), 256, 0, stream>>>(
        q, k, v, wq, wk, wv, wo, qb, kb, vb, wqb, wkb, wvb, wob);
    qkv64_kernel<<<dim3(768), 256, 0, stream>>>(
        qb, kb, vb, wqb, wkb, wvb, Qp, Kp, VtG);
    attn8_kernel<<<dim3(512), 256, 0, stream>>>(Qp, Kp, VtG, AO);
    oproj64_kernel<<<dim3(512), 256, 0, stream>>>(AO, wob, out);
  } else {
    qkv_f32_kernel<<<dim3(768), 256, 0, stream>>>(
        q, k, v, wq, wk, wv, Qp, Kp, VtG);
    attn8_kernel<<<dim3(512), 256, 0, stream>>>(Qp, Kp, VtG, AO);
    oproj_f32_kernel<<<dim3(256), 256, 0, stream>>>(AO, wo, out);
  }
}

// Round 10
// 201.843 us; speedup vs baseline: 1.9601x; 1.0303x over previous
//
#include <hip/hip_runtime.h>
#include <cstdint>
#include <cstddef>

typedef __bf16 bf16;
typedef __attribute__((ext_vector_type(4))) __bf16 bf16x4;
typedef __attribute__((ext_vector_type(8))) __bf16 bf16x8;
typedef __attribute__((ext_vector_type(4))) float floatx4;
typedef __attribute__((ext_vector_type(4))) short short4v;

#define MFMA16(a, b, c) __builtin_amdgcn_mfma_f32_16x16x32_bf16((a), (b), (c), 0, 0, 0)

// K=16 bf16 MFMA: A[m=l16][k=quad*4+j], B[n=l16][k=quad*4+j], C row=quad*4+r col=l16
__device__ __forceinline__ floatx4 MFMAK16(bf16x4 a, bf16x4 b, floatx4 c) {
#if __has_builtin(__builtin_amdgcn_mfma_f32_16x16x16bf16_1k)
  return __builtin_amdgcn_mfma_f32_16x16x16bf16_1k(
      __builtin_bit_cast(short4v, a), __builtin_bit_cast(short4v, b), c, 0, 0, 0);
#else
  floatx4 d;
  asm("v_mfma_f32_16x16x16_bf16 %0, %1, %2, %3"
      : "=v"(d)
      : "v"(a), "v"(b), "v"(c));
  return d;
#endif
}

constexpr int DMODEL = 1024;
constexpr int NH = 16;
constexpr int DKH = 64;
constexpr int B_ = 2;
constexpr int S_ = 2048;
constexpr int MTOT = B_ * S_;  // 4096
constexpr float CEXP = 0.125f * 1.44269504f;  // log2(e)/sqrt(64), folded into Q

// async global->LDS, 16B/lane; LDS dest = wave-uniform base + lane*16
__device__ __forceinline__ void load_lds16(const void* g, void* l) {
  __builtin_amdgcn_global_load_lds(
      (const __attribute__((address_space(1))) uint32_t*)g,
      (__attribute__((address_space(3))) uint32_t*)l, 16, 0, 0);
}

// ---------------------------------------------------------------------------
// Swizzled LDS tiles: 64-col bf16 rows (8 x 16B chunks/row), chunk swizzle
// s = c ^ (row & 7); reads via frag64 (b128) / frag64h (b64) -> <=2-way banks.
// ---------------------------------------------------------------------------
__device__ __forceinline__ bf16x8 frag64(const bf16* lds, int row, int p) {
  int s = p ^ (row & 7);
  return *(const bf16x8*)&lds[row * 64 + s * 8];
}
// 8B read at global chunk p (16B units), sub-half h (0/1)
__device__ __forceinline__ bf16x4 frag64h(const bf16* lds, int row, int p, int h) {
  int s = p ^ (row & 7);
  return *(const bf16x4*)&lds[row * 64 + s * 8 + h * 4];
}

// 32-col variants (BK=32 fallback path)
__device__ __forceinline__ void stage32_bf16(const bf16* __restrict__ src,
                                             bf16* lds, int wave, int lane,
                                             int ldg) {
#pragma unroll
  for (int i = 0; i < 2; ++i) {
    int cb = (wave * 2 + i) * 64;
    int c = cb + lane;
    int r = c >> 2;
    int s = (c & 3) ^ ((r >> 1) & 3);
    load_lds16(&src[(size_t)r * ldg + s * 8], &lds[cb * 8]);
  }
}
__device__ __forceinline__ bf16x8 frag32_bf16(const bf16* lds, int row,
                                              int quad) {
  int s = quad ^ ((row >> 1) & 3);
  return *(const bf16x8*)&lds[row * 32 + s * 8];
}
__device__ __forceinline__ void stage32_f32(const float* __restrict__ src,
                                            float* lds, int wave, int lane,
                                            int ldg) {
#pragma unroll
  for (int i = 0; i < 4; ++i) {
    int cb = (wave * 4 + i) * 64;
    int c = cb + lane;
    int r = c >> 3;
    int s = (c & 7) ^ (r & 7);
    load_lds16(&src[(size_t)r * ldg + s * 4], &lds[cb * 4]);
  }
}
__device__ __forceinline__ bf16x8 frag32_f32(const float* lds, int row,
                                             int quad) {
  int s1 = (2 * quad) ^ (row & 7);
  int s2 = (2 * quad + 1) ^ (row & 7);
  float4 a = *(const float4*)&lds[row * 32 + s1 * 4];
  float4 b = *(const float4*)&lds[row * 32 + s2 * 4];
  bf16x8 h = {(bf16)a.x, (bf16)a.y, (bf16)a.z, (bf16)a.w,
              (bf16)b.x, (bf16)b.y, (bf16)b.z, (bf16)b.w};
  return h;
}

// ---------------------------------------------------------------------------
// fp32 -> bf16 bulk convert (fast path only). Flat exact-size grid: 8192
// blocks. NOT fused into the GEMMs: R8 measured fp32 A-panels thrash the
// 4MB per-XCD L2 (FETCH 12->90MB). Pre-converting keeps panels L2-resident.
// ---------------------------------------------------------------------------
__global__ __launch_bounds__(256) void convert_kernel(
    const float* __restrict__ q, const float* __restrict__ k,
    const float* __restrict__ v, const float* __restrict__ wq,
    const float* __restrict__ wk, const float* __restrict__ wv,
    const float* __restrict__ wo, bf16* __restrict__ qb, bf16* __restrict__ kb,
    bf16* __restrict__ vb, bf16* __restrict__ wqb, bf16* __restrict__ wkb,
    bf16* __restrict__ wvb, bf16* __restrict__ wob) {
  const int bid = blockIdx.x;
  int seg, rel;
  if (bid < 6144) {
    seg = bid >> 11;        // 0..2 : q,k,v (2048 blocks each)
    rel = bid & 2047;
  } else {
    int t = bid - 6144;
    seg = 3 + (t >> 9);     // 3..6 : wq,wk,wv,wo (512 blocks each)
    rel = t & 511;
  }
  const float* src;
  bf16* dst;
  switch (seg) {
    case 0: src = q;  dst = qb;  break;
    case 1: src = k;  dst = kb;  break;
    case 2: src = v;  dst = vb;  break;
    case 3: src = wq; dst = wqb; break;
    case 4: src = wk; dst = wkb; break;
    case 5: src = wv; dst = wvb; break;
    default: src = wo; dst = wob; break;
  }
  size_t idx = ((size_t)rel * 256 + threadIdx.x) * 8;
  float4 f0 = *(const float4*)&src[idx];
  float4 f1 = *(const float4*)&src[idx + 4];
  bf16x8 h = {(bf16)f0.x, (bf16)f0.y, (bf16)f0.z, (bf16)f0.w,
              (bf16)f1.x, (bf16)f1.y, (bf16)f1.z, (bf16)f1.w};
  *(bf16x8*)&dst[idx] = h;
}

// ---------------------------------------------------------------------------
// gemm64: bf16 GEMM, 128x128 tile, BK=64, 4 waves. C-store scaled by ascale.
// vt path: Vt store via LDS transpose -> coalesced 16B stores. smem overlay:
// As/Bs staging (32KB) and T[128][136] transpose buffer share one allocation.
// ---------------------------------------------------------------------------
template <typename TC>
__device__ __forceinline__ void gemm64(const bf16* __restrict__ A,
                                       const bf16* __restrict__ W,
                                       TC* __restrict__ C,
                                       bf16* __restrict__ vt, int K,
                                       int m0, int n0, float ascale) {
  constexpr int N = DMODEL;
  __shared__ alignas(16) bf16 smem[128 * 136];  // max(As+Bs, T)
  bf16* As = smem;            // 128*64
  bf16* Bs = smem + 128 * 64; // 128*64

  const int tid = threadIdx.x;
  const int wave = tid >> 6;
  const int lane = tid & 63;
  const int quad = lane >> 4;
  const int l16 = lane & 15;
  const int wm = (wave >> 1) * 64;
  const int wn = (wave & 1) * 64;

  floatx4 acc[4][4] = {};

  for (int k0 = 0; k0 < K; k0 += 64) {
#pragma unroll
    for (int i = 0; i < 4; ++i) {
      int cb = (wave * 4 + i) * 64;
      int c = cb + lane;
      int r = c >> 3;
      int s = (c & 7) ^ (r & 7);
      load_lds16(&A[(size_t)(m0 + r) * K + k0 + s * 8], &As[cb * 8]);
      load_lds16(&W[(size_t)(n0 + r) * K + k0 + s * 8], &Bs[cb * 8]);
    }
    __syncthreads();

#pragma unroll
    for (int kk = 0; kk < 2; ++kk) {
      bf16x8 af[4], bfv[4];
#pragma unroll
      for (int mi = 0; mi < 4; ++mi)
        af[mi] = frag64(As, wm + mi * 16 + l16, kk * 4 + quad);
#pragma unroll
      for (int ni = 0; ni < 4; ++ni)
        bfv[ni] = frag64(Bs, wn + ni * 16 + l16, kk * 4 + quad);
#pragma unroll
      for (int mi = 0; mi < 4; ++mi)
#pragma unroll
        for (int ni = 0; ni < 4; ++ni)
          acc[mi][ni] = MFMA16(af[mi], bfv[ni], acc[mi][ni]);
    }
    __syncthreads();
  }

  if (vt) {
    // transpose epilogue: acc -> T[col][row] (pad 136 -> ~2-way banks),
    // then coalesced 16B row-stores of Vt[d][s].
    bf16* T = smem;
#pragma unroll
    for (int mi = 0; mi < 4; ++mi)
#pragma unroll
      for (int ni = 0; ni < 4; ++ni) {
        int row = wm + mi * 16 + quad * 4;      // +r contiguous
        int col = wn + ni * 16 + l16;
        bf16x4 vvv = {(bf16)acc[mi][ni][0], (bf16)acc[mi][ni][1],
                      (bf16)acc[mi][ni][2], (bf16)acc[mi][ni][3]};
        *(bf16x4*)&T[col * 136 + row] = vvv;
      }
    __syncthreads();
    const int bb = m0 >> 11;
    const int sbase = (m0 & 2047) + l16 * 8;
#pragma unroll
    for (int jj = 0; jj < 8; ++jj) {
      int colv = wave * 32 + jj * 4 + quad;
      int gcol = n0 + colv;
      int h = gcol >> 6, d = gcol & 63;
      bf16x8 rowv = *(const bf16x8*)&T[colv * 136 + l16 * 8];
      *(bf16x8*)&vt[(size_t)((bb * NH + h) * DKH + d) * S_ + sbase] = rowv;
    }
  } else {
#pragma unroll
    for (int mi = 0; mi < 4; ++mi)
#pragma unroll
      for (int ni = 0; ni < 4; ++ni)
#pragma unroll
        for (int r = 0; r < 4; ++r) {
          int row = m0 + wm + mi * 16 + quad * 4 + r;
          int col = n0 + wn + ni * 16 + l16;
          C[(size_t)row * N + col] = (TC)(acc[mi][ni][r] * ascale);
        }
  }
}

// qkv fast path: flat grid 768, XCD row-ownership (bid&7 = XCD round-robin).
__global__ __launch_bounds__(256, 3) void qkv64_kernel(
    const bf16* __restrict__ q, const bf16* __restrict__ k,
    const bf16* __restrict__ v, const bf16* __restrict__ wq,
    const bf16* __restrict__ wk, const bf16* __restrict__ wv,
    bf16* __restrict__ Q, bf16* __restrict__ K, bf16* __restrict__ Vt) {
  const int bid = blockIdx.x;
  const int xcd = bid & 7;
  const int j = bid >> 3;
  const int n = j & 7;
  const int rowslot = j >> 3;
  const int p = xcd * 12 + rowslot;
  const int z = p >> 5;
  const int y = p & 31;

  const bf16* A = (z == 0) ? q : (z == 1) ? k : v;
  const bf16* W = (z == 0) ? wq : (z == 1) ? wk : wv;
  bf16* C = (z == 0) ? Q : K;
  gemm64<bf16>(A, W, (z == 2) ? nullptr : C, (z == 2) ? Vt : nullptr,
               DMODEL, y * 128, n * 128, (z == 0) ? CEXP : 1.0f);
}

// oproj fast path: BM=64, BN=128, BK=64 -> grid 512 (2 blocks/CU), LDS 24KB.
__global__ __launch_bounds__(256) void oproj64_kernel(
    const bf16* __restrict__ A, const bf16* __restrict__ W,
    float* __restrict__ C) {
  constexpr int K = DMODEL;
  constexpr int N = DMODEL;
  __shared__ alignas(16) bf16 As[64 * 64];
  __shared__ alignas(16) bf16 Bs[128 * 64];

  const int bid = blockIdx.x;
  const int xcd = bid & 7;
  const int j = bid >> 3;
  const int n = j & 7;
  const int slot = j >> 3;
  const int mt = xcd * 8 + slot;
  const int m0 = mt * 64;
  const int n0 = n * 128;

  const int tid = threadIdx.x;
  const int wave = tid >> 6;
  const int lane = tid & 63;
  const int quad = lane >> 4;
  const int l16 = lane & 15;
  const int wm = (wave >> 1) * 32;
  const int wn = (wave & 1) * 64;

  floatx4 acc[2][4] = {};

  for (int k0 = 0; k0 < K; k0 += 64) {
#pragma unroll
    for (int i = 0; i < 2; ++i) {
      int cb = (wave * 2 + i) * 64;
      int c = cb + lane;
      int r = c >> 3;
      int s = (c & 7) ^ (r & 7);
      load_lds16(&A[(size_t)(m0 + r) * K + k0 + s * 8], &As[cb * 8]);
    }
#pragma unroll
    for (int i = 0; i < 4; ++i) {
      int cb = (wave * 4 + i) * 64;
      int c = cb + lane;
      int r = c >> 3;
      int s = (c & 7) ^ (r & 7);
      load_lds16(&W[(size_t)(n0 + r) * K + k0 + s * 8], &Bs[cb * 8]);
    }
    __syncthreads();

#pragma unroll
    for (int kk = 0; kk < 2; ++kk) {
      bf16x8 af[2], bfv[4];
#pragma unroll
      for (int mi = 0; mi < 2; ++mi)
        af[mi] = frag64(As, wm + mi * 16 + l16, kk * 4 + quad);
#pragma unroll
      for (int ni = 0; ni < 4; ++ni)
        bfv[ni] = frag64(Bs, wn + ni * 16 + l16, kk * 4 + quad);
#pragma unroll
      for (int mi = 0; mi < 2; ++mi)
#pragma unroll
        for (int ni = 0; ni < 4; ++ni)
          acc[mi][ni] = MFMA16(af[mi], bfv[ni], acc[mi][ni]);
    }
    __syncthreads();
  }

#pragma unroll
  for (int mi = 0; mi < 2; ++mi)
#pragma unroll
    for (int ni = 0; ni < 4; ++ni)
#pragma unroll
      for (int r = 0; r < 4; ++r) {
        int row = m0 + wm + mi * 16 + quad * 4 + r;
        int col = n0 + wn + ni * 16 + l16;
        C[(size_t)row * N + col] = acc[mi][ni][r];
      }
}

// ---------------------------------------------------------------------------
// Fallback (ws < 64MB): fp32-input GEMM, BK=32. ascale folds CEXP into Q.
// ---------------------------------------------------------------------------
template <typename TA, typename TW, typename TC>
__device__ __forceinline__ void gemm_core(const TA* __restrict__ A,
                                          const TW* __restrict__ W,
                                          TC* __restrict__ C,
                                          bf16* __restrict__ vt, int K,
                                          int m0, int n0, float ascale) {
  constexpr int N = DMODEL;
  __shared__ alignas(16) char smem[128 * 32 * (sizeof(TA) + sizeof(TW))];
  TA* As = (TA*)smem;
  TW* Bs = (TW*)(smem + 128 * 32 * sizeof(TA));

  const int tid = threadIdx.x;
  const int wave = tid >> 6;
  const int lane = tid & 63;
  const int quad = lane >> 4;
  const int l16 = lane & 15;
  const int wm = (wave >> 1) * 64;
  const int wn = (wave & 1) * 64;

  floatx4 acc[4][4] = {};

  for (int k0 = 0; k0 < K; k0 += 32) {
    if constexpr (sizeof(TA) == 2)
      stage32_bf16((const bf16*)A + (size_t)m0 * K + k0, (bf16*)As, wave, lane, K);
    else
      stage32_f32((const float*)A + (size_t)m0 * K + k0, (float*)As, wave, lane, K);
    if constexpr (sizeof(TW) == 2)
      stage32_bf16((const bf16*)W + (size_t)n0 * K + k0, (bf16*)Bs, wave, lane, K);
    else
      stage32_f32((const float*)W + (size_t)n0 * K + k0, (float*)Bs, wave, lane, K);
    __syncthreads();

    bf16x8 af[4], bfv[4];
#pragma unroll
    for (int mi = 0; mi < 4; ++mi) {
      if constexpr (sizeof(TA) == 2)
        af[mi] = frag32_bf16((const bf16*)As, wm + mi * 16 + l16, quad);
      else
        af[mi] = frag32_f32((const float*)As, wm + mi * 16 + l16, quad);
    }
#pragma unroll
    for (int ni = 0; ni < 4; ++ni) {
      if constexpr (sizeof(TW) == 2)
        bfv[ni] = frag32_bf16((const bf16*)Bs, wn + ni * 16 + l16, quad);
      else
        bfv[ni] = frag32_f32((const float*)Bs, wn + ni * 16 + l16, quad);
    }
#pragma unroll
    for (int mi = 0; mi < 4; ++mi)
#pragma unroll
      for (int ni = 0; ni < 4; ++ni)
        acc[mi][ni] = MFMA16(af[mi], bfv[ni], acc[mi][ni]);
    __syncthreads();
  }

  if (vt) {
#pragma unroll
    for (int mi = 0; mi < 4; ++mi)
#pragma unroll
      for (int ni = 0; ni < 4; ++ni)
#pragma unroll
        for (int r = 0; r < 4; ++r) {
          int row = m0 + wm + mi * 16 + quad * 4 + r;
          int col = n0 + wn + ni * 16 + l16;
          int bb = row >> 11, s = row & 2047;
          int h = col >> 6, d = col & 63;
          vt[(size_t)((bb * NH + h) * DKH + d) * S_ + s] = (bf16)acc[mi][ni][r];
        }
  } else {
#pragma unroll
    for (int mi = 0; mi < 4; ++mi)
#pragma unroll
      for (int ni = 0; ni < 4; ++ni)
#pragma unroll
        for (int r = 0; r < 4; ++r) {
          int row = m0 + wm + mi * 16 + quad * 4 + r;
          int col = n0 + wn + ni * 16 + l16;
          C[(size_t)row * N + col] = (TC)(acc[mi][ni][r] * ascale);
        }
  }
}

__global__ __launch_bounds__(256) void qkv_f32_kernel(
    const float* __restrict__ q, const float* __restrict__ k,
    const float* __restrict__ v, const float* __restrict__ wq,
    const float* __restrict__ wk, const float* __restrict__ wv,
    bf16* __restrict__ Q, bf16* __restrict__ K, bf16* __restrict__ Vt) {
  const int bid = blockIdx.x;
  const int xcd = bid & 7;
  const int j = bid >> 3;
  const int n = j & 7;
  const int rowslot = j >> 3;
  const int p = xcd * 12 + rowslot;
  const int z = p >> 5;
  const int y = p & 31;
  const float* A = (z == 0) ? q : (z == 1) ? k : v;
  const float* W = (z == 0) ? wq : (z == 1) ? wk : wv;
  bf16* C = (z == 0) ? Q : K;
  gemm_core<float, float, bf16>(A, W, (z == 2) ? nullptr : C,
                                (z == 2) ? Vt : nullptr, DMODEL, y * 128,
                                n * 128, (z == 0) ? CEXP : 1.0f);
}

__global__ __launch_bounds__(256) void oproj_f32_kernel(
    const bf16* __restrict__ A, const float* __restrict__ W,
    float* __restrict__ C) {
  const int bid = blockIdx.x;
  const int xcd = bid & 7;
  const int j = bid >> 3;
  const int n = j & 7;
  const int rowslot = j >> 3;
  const int y = xcd * 4 + rowslot;
  gemm_core<bf16, float, float>(A, W, C, nullptr, DMODEL, y * 128, n * 128,
                                1.0f);
}

// ---------------------------------------------------------------------------
// Causal flash attention v12: 2 causal pairs per block + key-half split.
// 256 blocks x 512 threads (8 waves), 1 block/CU (8 waves = 2/SIMD, same
// residency as v8's measured occupancy). Block pg owns q-tiles
// {2pg, 2pg+1, 30-2pg, 31-2pg} (66 units, balanced); all four share one
// K/V staging stream (prefix property). Wave (kh=w&1, ws=w>>1): ws = 16-q
// slice, kh = 32-key half. Per iteration a wave reads 8KB of fragments
// (HALF of v8's 16KB) feeding up to 4 independent tile-chains (v8: 2)
// -> LDS-pipe demand ~2x down, per-wave ILP 2x up, at equal occupancy.
// Fixed-max softmax => partials additive; one-time LDS combine across kh.
// LDS 64KB (32KB K/V dbuf + epilogue overlay).
// ---------------------------------------------------------------------------
__device__ __forceinline__ void stage_one(const bf16* __restrict__ K,
                                          const bf16* __restrict__ Vt,
                                          bf16* Ks, bf16* Vts, size_t baseQ,
                                          size_t baseV, int kt, int wave,
                                          int lane) {
  // 512 threads stage one 64x64 K tile + one 64x64 V^T tile (8KB each):
  // 1 x 16B chunk of each per lane.
  int cb = wave * 64;
  int c = cb + lane;           // 0..511
  int r = c >> 3;              // 0..63
  int s = (c & 7) ^ (r & 7);
  load_lds16(&K[baseQ + (size_t)(kt * 64 + r) * DMODEL + s * 8], &Ks[cb * 8]);
  load_lds16(&Vt[baseV + (size_t)r * S_ + kt * 64 + s * 8], &Vts[cb * 8]);
}

// one 32-key half-tile for one 16-q slice, from preloaded ka/va fragments
template <bool DIAG>
__device__ __forceinline__ void tile_half(const bf16x8 (&ka)[2][2],
                                          const bf16x4 (&va)[2][4],
                                          const bf16x8 qf[2], floatx4 (&ot)[4],
                                          float& lp, int quad, int qb, int kh) {
  floatx4 sa[2] = {};
#pragma unroll
  for (int kk = 0; kk < 2; ++kk)
#pragma unroll
    for (int kg = 0; kg < 2; ++kg)
      sa[kg] = MFMA16(ka[kk][kg], qf[kk], sa[kg]);

  bf16x4 pb[2];
#pragma unroll
  for (int kg = 0; kg < 2; ++kg) {
    float pv[4];
#pragma unroll
    for (int r = 0; r < 4; ++r) {
      float s = sa[kg][r];
      if (DIAG) {
        int key = kh * 32 + kg * 16 + quad * 4 + r;
        s = (key > qb) ? -3.0e38f : s;
      }
      float p = __builtin_amdgcn_exp2f(s);
      lp += p;
      pv[r] = p;
    }
    pb[kg] = bf16x4{(bf16)pv[0], (bf16)pv[1], (bf16)pv[2], (bf16)pv[3]};
  }

#pragma unroll
  for (int kg = 0; kg < 2; ++kg)
#pragma unroll
    for (int di = 0; di < 4; ++di)
      ot[di] = MFMAK16(va[kg][di], pb[kg], ot[di]);
}

__global__ __launch_bounds__(512, 2) void attn12_kernel(
    const bf16* __restrict__ Q, const bf16* __restrict__ K,
    const bf16* __restrict__ Vt, bf16* __restrict__ O) {
  __shared__ alignas(16) char smem[65536];
  bf16* KsB = (bf16*)smem;             // [2][64*64] = 16KB
  bf16* VtsB = (bf16*)(smem + 16384);  // [2][64*64] = 16KB

  const int tid = threadIdx.x;
  const int wave = tid >> 6;
  const int lane = tid & 63;
  const int quad = lane >> 4;
  const int l16 = lane & 15;
  const int ws = wave >> 1;  // 16-q slice (0..3)
  const int kh = wave & 1;   // key half (0..1)

  const int j = blockIdx.x;
  const int bh = j & 31;     // bid&7 = bh&7: heads spread across XCDs
  const int pg = j >> 5;     // 0..7: pairs (2pg,31-2pg) and (2pg+1,30-2pg)
  const int qt[4] = {2 * pg, 2 * pg + 1, 30 - 2 * pg, 31 - 2 * pg};
  const int h = bh & 15;
  const int b = bh >> 4;
  const size_t baseQ = (size_t)b * S_ * DMODEL + (size_t)h * DKH;
  const size_t baseV = (size_t)bh * DKH * S_;

  // Q fragments in B-operand layout (lane=q, k=quad*8+j), pre-scaled by CEXP
  bf16x8 qf[4][2];
#pragma unroll
  for (int t = 0; t < 4; ++t)
#pragma unroll
    for (int kk = 0; kk < 2; ++kk)
      qf[t][kk] = *(const bf16x8*)&Q[baseQ +
          (size_t)(qt[t] * 64 + ws * 16 + l16) * DMODEL + kk * 32 + quad * 8];

  floatx4 ot[4][4] = {};  // [tile][di]: O^T partials (this key-half)
  float lp[4] = {};       // l partials
  const int qb = ws * 16 + l16;  // q index within each 64-row tile

  const int NIT = 32 - 2 * pg;   // qt[3]+1 iterations

  stage_one(K, Vt, KsB, VtsB, baseQ, baseV, 0, wave, lane);
  __syncthreads();  // drains vmcnt(0)

  for (int kt = 0; kt < NIT; ++kt) {
    const int cur = kt & 1;
    if (kt + 1 < NIT)  // prefetch next tile; latency hides under compute
      stage_one(K, Vt, KsB + (cur ^ 1) * 4096, VtsB + (cur ^ 1) * 4096,
                baseQ, baseV, kt + 1, wave, lane);

    __builtin_amdgcn_s_setprio(1);
    const bf16* ks = KsB + cur * 4096;
    const bf16* vs = VtsB + cur * 4096;

    // load this key-half's fragments ONCE; they feed up to 4 tile-chains
    bf16x8 ka[2][2];
#pragma unroll
    for (int kk = 0; kk < 2; ++kk)
#pragma unroll
      for (int kg = 0; kg < 2; ++kg)
        ka[kk][kg] = frag64(ks, kh * 32 + kg * 16 + l16, kk * 4 + quad);
    bf16x4 va[2][4];
#pragma unroll
    for (int kg = 0; kg < 2; ++kg)
#pragma unroll
      for (int di = 0; di < 4; ++di)
        va[kg][di] = frag64h(vs, di * 16 + l16,
                             (kh * 2 + kg) * 2 + (quad >> 1), quad & 1);

#pragma unroll
    for (int t = 0; t < 4; ++t) {
      if (kt < qt[t])
        tile_half<false>(ka, va, qf[t], ot[t], lp[t], quad, qb, kh);
      else if (kt == qt[t])
        tile_half<true>(ka, va, qf[t], ot[t], lp[t], quad, qb, kh);
    }
    __builtin_amdgcn_s_setprio(0);

    __syncthreads();  // next buffer staged; this one free
  }

  // cross-key-half combine: partials additive (fixed-max softmax).
  // kh=1 publishes via LDS overlay; kh=0 merges + stores.
  floatx4* ox = (floatx4*)smem;  // [ws][t][di][lane] : 4*4*4*64*16B = 64KB
  if (kh == 1) {
#pragma unroll
    for (int t = 0; t < 4; ++t)
#pragma unroll
      for (int di = 0; di < 4; ++di)
        ox[((ws * 4 + t) * 4 + di) * 64 + lane] = ot[t][di];
  }
  __syncthreads();
  if (kh == 0) {
#pragma unroll
    for (int t = 0; t < 4; ++t)
#pragma unroll
      for (int di = 0; di < 4; ++di)
        ot[t][di] += ox[((ws * 4 + t) * 4 + di) * 64 + lane];
  }
  __syncthreads();
  float* lx = (float*)smem;  // [ws][t][lane] : 4*4*64 floats = 4KB
  if (kh == 1) {
#pragma unroll
    for (int t = 0; t < 4; ++t)
      lx[(ws * 4 + t) * 64 + lane] = lp[t];
  }
  __syncthreads();
  if (kh == 0) {
#pragma unroll
    for (int t = 0; t < 4; ++t) {
      float l = lp[t] + lx[(ws * 4 + t) * 64 + lane];
      l += __shfl_xor(l, 16, 64);
      l += __shfl_xor(l, 32, 64);
      const float inv = 1.0f / l;
      const size_t orow = baseQ +
          (size_t)(qt[t] * 64 + ws * 16 + l16) * DMODEL;
#pragma unroll
      for (int di = 0; di < 4; ++di)
#pragma unroll
        for (int r = 0; r < 4; ++r)
          O[orow + di * 16 + quad * 4 + r] = (bf16)(ot[t][di][r] * inv);
    }
  }
}

// ---------------------------------------------------------------------------
extern "C" void kernel_launch(void* const* d_in, const int* in_sizes, int n_in,
                              void* d_out, int out_size, void* d_ws,
                              size_t ws_size, hipStream_t stream) {
  const float* q = (const float*)d_in[0];
  const float* k = (const float*)d_in[1];
  const float* v = (const float*)d_in[2];
  // d_in[3] = causal mask: static tril, computed analytically in-kernel
  const float* wq = (const float*)d_in[4];
  const float* wk = (const float*)d_in[5];
  const float* wv = (const float*)d_in[6];
  const float* wo = (const float*)d_in[7];
  float* out = (float*)d_out;

  const size_t MB = 1024 * 1024;
  char* base = (char*)d_ws;
  bf16* Qp = (bf16*)(base);
  bf16* Kp = (bf16*)(base + 8 * MB);
  bf16* VtG = (bf16*)(base + 16 * MB);
  bf16* AO = (bf16*)(base + 24 * MB);

  if (ws_size >= 64 * MB) {
    bf16* qb = (bf16*)(base + 32 * MB);
    bf16* kb = (bf16*)(base + 40 * MB);
    bf16* vb = (bf16*)(base + 48 * MB);
    bf16* wqb = (bf16*)(base + 56 * MB);
    bf16* wkb = (bf16*)(base + 58 * MB);
    bf16* wvb = (bf16*)(base + 60 * MB);
    bf16* wob = (bf16*)(base + 62 * MB);
    convert_kernel<<<dim3(8192), 256, 0, stream>>>(
        q, k, v, wq, wk, wv, wo, qb, kb, vb, wqb, wkb, wvb, wob);
    qkv64_kernel<<<dim3(768), 256, 0, stream>>>(
        qb, kb, vb, wqb, wkb, wvb, Qp, Kp, VtG);
    attn12_kernel<<<dim3(256), 512, 0, stream>>>(Qp, Kp, VtG, AO);
    oproj64_kernel<<<dim3(512), 256, 0, stream>>>(AO, wob, out);
  } else {
    qkv_f32_kernel<<<dim3(768), 256, 0, stream>>>(
        q, k, v, wq, wk, wv, Qp, Kp, VtG);
    attn12_kernel<<<dim3(256), 512, 0, stream>>>(Qp, Kp, VtG, AO);
    oproj_f32_kernel<<<dim3(256), 256, 0, stream>>>(AO, wo, out);
  }
}